// Round 5
// baseline (446.472 us; speedup 1.0000x reference)
//
#include <hip/hip_runtime.h>
#include <hip/hip_bf16.h>

#define NN 64
#define BATCH 512
#define SP 60
#define SG 180
#define SEX 10
#define CATD 80
#define NA 5
#define NR 7
#define OO 8
#define II 8

typedef unsigned long long u64;
typedef unsigned short u16;
typedef unsigned int u32;

// ---- workspace layout (float offsets) ----
#define OFF_Z     0
#define OFF_DZ    327680
#define OFF_HAS   655360
#define OFF_WIHF  688128
#define OFF_WHHF  698928
#define OFF_BIHF  709728
#define OFF_BHHF  709908
#define OFF_WIHB  710088
#define OFF_WHHB  720888
#define OFF_BIHB  731688
#define OFF_BHHB  731868
#define OFF_WF    732048
#define OFF_BF    736848
#define OFF_WB    736908
#define OFF_BB    741708
#define OFF_WA    741768
#define OFF_BA    742368
#define OFF_WC    742373
#define OFF_BC    742493
#define OFF_WU    742494
#define OFF_BU    743334
#define CONV_TOTAL 743341
#define OFF_FLAG  743342
#define OFF_RHOF  743344
#define OFF_RHOB  (OFF_RHOF + 1966080)
#define OFF_ALF   (OFF_RHOB + 1966080)
#define OFF_ALB   (OFF_ALF + 30720)
#define OUT_TOTAL 232448

typedef _Float16 f16;
typedef _Float16 half2_t __attribute__((ext_vector_type(2)));

__device__ __forceinline__ float us2f(u16 v){
  return __uint_as_float(((u32)v) << 16);
}
__device__ __forceinline__ u16 f2bf(float f){
  __hip_bfloat16 h = __float2bfloat16(f);
  return *reinterpret_cast<u16*>(&h);
}
__device__ __forceinline__ float sigm(float x){ return 1.f/(1.f+__expf(-x)); }
__device__ __forceinline__ float tanh_(float x){
  float ax = fabsf(x);
  float e = __expf(-2.f*ax);
  float t = (1.f - e)/(1.f + e);
  return copysignf(t, x);
}
__device__ __forceinline__ u32 pack2(float a, float b){
  half2_t h; h[0] = (f16)a; h[1] = (f16)b;
  return __builtin_bit_cast(u32, h);
}
__device__ __forceinline__ float fdot2_(u32 a, u32 b, float c){
  return __builtin_amdgcn_fdot2(__builtin_bit_cast(half2_t, a),
                                __builtin_bit_cast(half2_t, b), c, false);
}

struct HP { uint4 q[8]; };
__device__ __forceinline__ u32 hpc(const HP& p, int k){
  const uint4& v = p.q[k>>2];
  switch(k&3){ case 0: return v.x; case 1: return v.y; case 2: return v.z; default: return v.w; }
}

#define LOAD_HP(P, I) do { const uint4* _r=(const uint4*)&sH4[I][0]; \
  _Pragma("unroll") for(int _k=0;_k<8;_k++) (P).q[_k]=_r[_k]; } while(0)

#define OWNH(I) ((float)*(const f16*)((const char*)&sH4[I][0] + 2*u))

#define GATE_DOTS(WR, WZ, WN, P, AR, AZ, AN) do { \
  float _r0=0.f,_r1=0.f,_z0=0.f,_z1=0.f,_n0=0.f,_n1=0.f; \
  _Pragma("unroll") \
  for (int k=0;k<30;k+=2){ \
    u32 _h0 = hpc(P,k), _h1 = hpc(P,k+1); \
    _r0=fdot2_(WR[k],_h0,_r0); _r1=fdot2_(WR[k+1],_h1,_r1); \
    _z0=fdot2_(WZ[k],_h0,_z0); _z1=fdot2_(WZ[k+1],_h1,_z1); \
    _n0=fdot2_(WN[k],_h0,_n0); _n1=fdot2_(WN[k+1],_h1,_n1); \
  } \
  AR=_r0+_r1; AZ=_z0+_z1; AN=_n0+_n1; \
} while(0)

// has is exactly {0,1}. f32 words: only 0x00000000 / 0x3F800000.
__device__ __forceinline__ int detect_bf16(const u32* w){
  int f = 0;
  for (int i=0;i<256;i++) f |= (w[i] == 0x3F803F80u) ? 1 : 0;
  return f;
}

__global__ __launch_bounds__(256) void conv_in(
  const void* z, const void* dz, const void* has,
  const void* WihF, const void* WhhF, const void* bihF, const void* bhhF,
  const void* WihB, const void* WhhB, const void* bihB, const void* bhhB,
  const void* Wf_, const void* bf_, const void* Wb_, const void* bb_,
  const void* Wa, const void* ba, const void* Wc, const void* bc,
  const void* Wu, const void* bu, float* ws)
{
  const int isbf = detect_bf16((const u32*)has);
  if (blockIdx.x == 0 && threadIdx.x == 0) ws[OFF_FLAG] = (float)isbf;
  int idx = blockIdx.x*256 + threadIdx.x;
  if (idx >= CONV_TOTAL) return;
  const void* src; int loc;
  if      (idx < OFF_DZ  ){ src=z;    loc=idx-OFF_Z;    }
  else if (idx < OFF_HAS ){ src=dz;   loc=idx-OFF_DZ;   }
  else if (idx < OFF_WIHF){ src=has;  loc=idx-OFF_HAS;  }
  else if (idx < OFF_WHHF){ src=WihF; loc=idx-OFF_WIHF; }
  else if (idx < OFF_BIHF){ src=WhhF; loc=idx-OFF_WHHF; }
  else if (idx < OFF_BHHF){ src=bihF; loc=idx-OFF_BIHF; }
  else if (idx < OFF_WIHB){ src=bhhF; loc=idx-OFF_BHHF; }
  else if (idx < OFF_WHHB){ src=WihB; loc=idx-OFF_WIHB; }
  else if (idx < OFF_BIHB){ src=WhhB; loc=idx-OFF_WHHB; }
  else if (idx < OFF_BHHB){ src=bihB; loc=idx-OFF_BIHB; }
  else if (idx < OFF_WF  ){ src=bhhB; loc=idx-OFF_BHHB; }
  else if (idx < OFF_BF  ){ src=Wf_;  loc=idx-OFF_WF;   }
  else if (idx < OFF_WB  ){ src=bf_;  loc=idx-OFF_BF;   }
  else if (idx < OFF_BB  ){ src=Wb_;  loc=idx-OFF_WB;   }
  else if (idx < OFF_WA  ){ src=bb_;  loc=idx-OFF_BB;   }
  else if (idx < OFF_BA  ){ src=Wa;   loc=idx-OFF_WA;   }
  else if (idx < OFF_WC  ){ src=ba;   loc=idx-OFF_BA;   }
  else if (idx < OFF_BC  ){ src=Wc;   loc=idx-OFF_WC;   }
  else if (idx < OFF_WU  ){ src=bc;   loc=idx-OFF_BC;   }
  else if (idx < OFF_BU  ){ src=Wu;   loc=idx-OFF_WU;   }
  else                    { src=bu;   loc=idx-OFF_BU;   }
  float v = isbf ? us2f(((const u16*)src)[loc]) : ((const float*)src)[loc];
  ws[idx] = v;
}

// Pipelined DAG-GRU: one wave (64 threads) per (batch row, direction).
// Lane u owns hidden unit u; Whh rows u,u+60,u+120 + Wcat row u live in VGPRs
// as packed f16 pairs (bf16->f16 exact). Wih lives in LDS (phase-2 only) to
// keep arch-VGPR demand < 256 so the hot Whh weights avoid AGPR shuffling.
__global__ __launch_bounds__(64, 1) void dir_kernel(const int* __restrict__ adj,
                                                    float* __restrict__ ws)
{
  const int u   = threadIdx.x;      // hidden unit (active < 60)
  const int bid = blockIdx.x;
  const int bwd = bid >> 9;
  const int b   = bid & 511;

  const float* Wih  = ws + (bwd ? OFF_WIHB : OFF_WIHF);
  const float* Whh  = ws + (bwd ? OFF_WHHB : OFF_WHHF);
  const float* bih  = ws + (bwd ? OFF_BIHB : OFF_BIHF);
  const float* bhh  = ws + (bwd ? OFF_BHHB : OFF_BHHF);
  const float* Wcat = ws + (bwd ? OFF_WB   : OFF_WF);
  const float* bcat = ws + (bwd ? OFF_BB   : OFF_BF);
  const float* zc   = ws + OFF_Z;
  const float* dzc  = ws + OFF_DZ;
  const float* hasc = ws + OFF_HAS;
  float* rho   = ws + (bwd ? OFF_RHOB : OFF_RHOF);  // [64][512][60]
  float* alpha = ws + (bwd ? OFF_ALB  : OFF_ALF);   // [512][60]

  __shared__ uint4 sH4[65][8];        // h[node][60] f16 pairs; row 64 = tail scratch
  __shared__ uint4 sRho4[8];          // current rho as f16 pairs
  __shared__ uint2 sWih2[15][192];    // Wih pairs-of-pairs: [kk][gate-row]
  __shared__ u32 sZp[NN][5];
  __shared__ u32 sDZp[NN][5];
  __shared__ float sHas[NN];
  __shared__ u16 sGiT[8][3][64];      // gi for tail nodes (bf16)
  __shared__ u64 sRowM[NN];
  __shared__ u64 sColM[NN];

  // ---- staging ----
  {
    u64 rowm = 0;
    for (int j=0;j<64;j++) rowm |= ((u64)(adj[u*64+j]!=0))<<j;
    sRowM[u] = rowm;
    sHas[u] = hasc[b*NN + u];
    for (int idx=u; idx<65*8; idx+=64) ((uint4*)sH4)[idx] = uint4{0,0,0,0};
    for (int idx=u; idx<NN*5; idx+=64){
      int n2=idx/5, p2=idx%5;
      sZp [n2][p2] = pack2(zc [(size_t)b*NN*SEX + n2*SEX + 2*p2],
                           zc [(size_t)b*NN*SEX + n2*SEX + 2*p2+1]);
      sDZp[n2][p2] = pack2(dzc[(size_t)b*NN*SEX + n2*SEX + 2*p2],
                           dzc[(size_t)b*NN*SEX + n2*SEX + 2*p2+1]);
    }
    for (int idx=u; idx<15*192; idx+=64){
      int kk = idx/192, r = idx%192;
      uint2 v = {0u, 0u};
      if (r < SG){
        v.x = pack2(Wih[r*SP + 4*kk    ], Wih[r*SP + 4*kk + 1]);
        v.y = pack2(Wih[r*SP + 4*kk + 2], Wih[r*SP + 4*kk + 3]);
      }
      sWih2[kk][r] = v;
    }
  }
  __syncthreads();
  {
    u64 colm = 0;
    for (int i2=0;i2<64;i2++) colm |= ((sRowM[i2]>>u)&1ULL)<<i2;
    sColM[u] = colm;
  }

  // per-lane hot weights (packed f16 pairs)
  u32 whr[30], whz[30], whn[30], wc[40];
  #pragma unroll
  for (int k=0;k<30;k++){
    whr[k] = pack2(Whh[(u     )*SP + 2*k], Whh[(u     )*SP + 2*k+1]);
    whz[k] = pack2(Whh[(u+ 60 )*SP + 2*k], Whh[(u+ 60 )*SP + 2*k+1]);
    whn[k] = pack2(Whh[(u+120 )*SP + 2*k], Whh[(u+120 )*SP + 2*k+1]);
  }
  #pragma unroll
  for (int k=0;k<40;k++) wc[k] = pack2(Wcat[u*CATD + 2*k], Wcat[u*CATD + 2*k+1]);
  const float bhr = bhh[u], bhz = bhh[u+60], bhn = bhh[u+120];
  const float bir = bih[u], biz = bih[u+60], bin_ = bih[u+120];
  const float bct = bcat[u];
  __syncthreads();

  // ---- 64 pipelined steps ----
  int t = bwd ? 63 : 0;
  const int dt = bwd ? -1 : 1;
  for (int s=0; s<64; s++, t+=dt){
    // phase 1: rho_t from h_t (+z_t, dz_t)
    {
      HP ht; LOAD_HP(ht, t);
      float c0 = bct, c1 = 0.f;
      #pragma unroll
      for (int k=0;k<30;k+=2){
        c0 = fdot2_(wc[k],   hpc(ht,k),   c0);
        c1 = fdot2_(wc[k+1], hpc(ht,k+1), c1);
      }
      #pragma unroll
      for (int p2=0;p2<5;p2++){
        c0 = fdot2_(wc[30+p2], sZp [t][p2], c0);
        c1 = fdot2_(wc[35+p2], sDZp[t][p2], c1);
      }
      float acc = c0 + c1;
      float rv = bwd ? acc : tanh_(acc);
      if (u < SP){
        rho[((size_t)t*BATCH + b)*SP + u] = rv;
        *(f16*)((char*)&sRho4[0] + 2*u) = (f16)rv;
      }
    }
    __syncthreads();
    // phase 2: gi_t = Wih @ rho_t + bih (3 values, in-lane; Wih from LDS)
    float gr, gz, gn;
    {
      HP rp;
      const uint4* _r = (const uint4*)&sRho4[0];
      #pragma unroll
      for (int _k=0;_k<8;_k++) rp.q[_k] = _r[_k];
      float r0=0.f,r1=0.f,z0=0.f,z1=0.f,n0v=0.f,n1v=0.f;
      #pragma unroll
      for (int kk=0;kk<15;kk++){
        uint2 wa = sWih2[kk][u];
        uint2 wb = sWih2[kk][u+60];
        uint2 wn2 = sWih2[kk][u+120];
        u32 h0 = hpc(rp,2*kk), h1 = hpc(rp,2*kk+1);
        r0  = fdot2_(wa.x,  h0, r0 );  r1  = fdot2_(wa.y,  h1, r1 );
        z0  = fdot2_(wb.x,  h0, z0 );  z1  = fdot2_(wb.y,  h1, z1 );
        n0v = fdot2_(wn2.x, h0, n0v);  n1v = fdot2_(wn2.y, h1, n1v);
      }
      gr = r0+r1+bir; gz = z0+z1+biz; gn = n0v+n1v+bin_;
    }
    const int slot = bwd ? t : (t - (NN-OO));
    if (slot >= 0 && slot < 8){
      sGiT[slot][0][u] = f2bf(gr); sGiT[slot][1][u] = f2bf(gz); sGiT[slot][2][u] = f2bf(gn);
    }
    // phase 3: advance all consumers of step t (uniform skip if has[b,t]==0)
    const float blendT = sHas[t];
    u64 m = bwd ? sColM[t] : sRowM[t];
    if (m && blendT != 0.f){
      int i = (int)__builtin_ctzll(m); m &= m-1;
      HP A; LOAD_HP(A, i);
      float holdA = OWNH(i);
      for (;;){
        int j = -1; HP B; float holdB = 0.f;
        if (m){ j = (int)__builtin_ctzll(m); m &= m-1;
                LOAD_HP(B, j); holdB = OWNH(j); }
        {
          float ar,az,an; GATE_DOTS(whr,whz,whn,A,ar,az,an);
          ar+=bhr; az+=bhz; an+=bhn;
          float r_=sigm(gr+ar), zg_=sigm(gz+az), nv_=tanh_(gn+r_*an);
          float hn_=(1.f-zg_)*nv_+zg_*holdA;
          float hw_=holdA+blendT*(hn_-holdA);
          if (u<SP) *(f16*)((char*)&sH4[i][0]+2*u) = (f16)hw_;
        }
        if (j < 0) break;
        int k2 = -1;
        if (m){ k2 = (int)__builtin_ctzll(m); m &= m-1;
                LOAD_HP(A, k2); holdA = OWNH(k2); }
        {
          float ar,az,an; GATE_DOTS(whr,whz,whn,B,ar,az,an);
          ar+=bhr; az+=bhz; an+=bhn;
          float r_=sigm(gr+ar), zg_=sigm(gz+az), nv_=tanh_(gn+r_*an);
          float hn_=(1.f-zg_)*nv_+zg_*holdB;
          float hw_=holdB+blendT*(hn_-holdB);
          if (u<SP) *(f16*)((char*)&sH4[j][0]+2*u) = (f16)hw_;
        }
        if (k2 < 0) break;
        i = k2;
      }
    }
    __syncthreads();
  }

  // ---- alpha tail: 8 plain GRU steps on scratch row 64 (zeroed at init) ----
  float hA = 0.f;
  for (int s2=0; s2<8; s2++){
    const int i = bwd ? (7 - s2) : (NN - OO + s2);
    const int slot = bwd ? i : (i - (NN-OO));
    HP P; LOAD_HP(P, 64);
    float ar,az,an; GATE_DOTS(whr,whz,whn,P,ar,az,an);
    ar+=bhr; az+=bhz; an+=bhn;
    float gr2=us2f(sGiT[slot][0][u]), gz2=us2f(sGiT[slot][1][u]), gn2=us2f(sGiT[slot][2][u]);
    float r_=sigm(gr2+ar), zg_=sigm(gz2+az), nv_=tanh_(gn2+r_*an);
    float hn_=(1.f-zg_)*nv_+zg_*hA;
    float blend = sHas[i];
    hA = hA + blend*(hn_-hA);
    __syncthreads();
    if (u<SP) *(f16*)((char*)&sH4[64][0]+2*u) = (f16)hA;
    __syncthreads();
  }
  if (u<SP) alpha[(size_t)b*SP + u] = hA;
}

// One block per batch element: psi + softmaxes, omega, value -> d_out directly.
__global__ __launch_bounds__(256, 1) void head_kernel(float* __restrict__ ws,
                                                      void* __restrict__ outp)
{
  const int b = blockIdx.x;
  const int tid = threadIdx.x;
  const int isbf = (ws[OFF_FLAG] != 0.f);
  const float* hasc   = ws + OFF_HAS;
  const float* WaC    = ws + OFF_WA;
  const float* baC    = ws + OFF_BA;
  const float* WcC    = ws + OFF_WC;
  const float* bcC    = ws + OFF_BC;
  const float* WuC    = ws + OFF_WU;
  const float* buC    = ws + OFF_BU;
  const float* rhoF   = ws + OFF_RHOF;
  const float* rhoB   = ws + OFF_RHOB;
  const float* alphaF = ws + OFF_ALF;
  const float* alphaB = ws + OFF_ALB;

  __shared__ float sF[NN][121];
  __shared__ float sAB[120];
  __shared__ float sWu[NR*120];
  __shared__ float sHasR[NN];
  __shared__ float sPsi[NR][NN];
  __shared__ float sRed[NR][2];
  __shared__ float sOm[NA];

  auto wout = [&](int idx, float v){
    if (isbf) ((u16*)outp)[idx] = f2bf(v);
    else      ((float*)outp)[idx] = v;
  };

  for (int idx=tid; idx<NN*SP; idx+=256){
    int n = idx/SP, s = idx%SP;
    sF[n][s]    = rhoF[((size_t)n*BATCH + b)*SP + s];
    sF[n][60+s] = rhoB[((size_t)n*BATCH + b)*SP + s];
  }
  for (int idx=tid; idx<120; idx+=256)
    sAB[idx] = (idx<60) ? alphaF[(size_t)b*SP + idx] : alphaB[(size_t)b*SP + idx-60];
  for (int idx=tid; idx<NR*120; idx+=256) sWu[idx] = WuC[idx];
  for (int idx=tid; idx<NN; idx+=256) sHasR[idx] = hasc[b*NN + idx];
  __syncthreads();

  for (int idx=tid; idx<NR*NN; idx+=256){
    int r = idx/NN, n = idx%NN;
    float acc = buC[r];
    for (int s=0;s<120;s++) acc += sF[n][s]*sWu[r*120+s];
    sPsi[r][n] = (sHasR[n] != 0.f) ? acc : -60.f;
  }
  if (tid >= 64 && tid < 64+NA){
    int a = tid - 64;
    float acc = baC[a];
    for (int s=0;s<120;s++) acc += sAB[s]*WaC[a*120+s];
    sOm[a] = acc;
  }
  if (tid == 70){
    float acc = bcC[0];
    for (int s=0;s<120;s++) acc += sAB[s]*WcC[s];
    wout(2560 + BATCH*NR*NN + b, acc);                 // value
  }
  __syncthreads();

  if (tid < NR){
    float m = -1e30f;
    for (int n=0;n<NN;n++) m = fmaxf(m, sPsi[tid][n]);
    float ssum = 0.f;
    for (int n=0;n<NN;n++) ssum += __expf(sPsi[tid][n]-m);
    sRed[tid][0] = m; sRed[tid][1] = 1.f/ssum;
  }
  if (tid == 8){
    float m = -1e30f;
    for (int a=0;a<NA;a++) m = fmaxf(m, sOm[a]);
    float e[NA]; float ssum = 0.f;
    for (int a=0;a<NA;a++){ e[a] = __expf(sOm[a]-m); ssum += e[a]; }
    for (int a=0;a<NA;a++) wout(b*NA + a, e[a]/ssum);  // instr_prob
  }
  __syncthreads();

  for (int idx=tid; idx<NR*NN; idx+=256){
    int r = idx/NN, n = idx%NN;
    float v = __expf(sPsi[r][n]-sRed[r][0]) * sRed[r][1];
    wout(2560 + (size_t)b*NR*NN + idx, v);             // role_prob
  }
}

extern "C" void kernel_launch(void* const* d_in, const int* in_sizes, int n_in,
                              void* d_out, int out_size, void* d_ws, size_t ws_size,
                              hipStream_t stream)
{
  const int* adj = (const int*)d_in[3];
  float* ws = (float*)d_ws;

  conv_in<<<(CONV_TOTAL+255)/256, 256, 0, stream>>>(
      d_in[0], d_in[1], d_in[2],
      d_in[4], d_in[5], d_in[6], d_in[7],
      d_in[8], d_in[9], d_in[10], d_in[11],
      d_in[12], d_in[13], d_in[14], d_in[15],
      d_in[16], d_in[17], d_in[18], d_in[19],
      d_in[20], d_in[21], ws);

  dir_kernel<<<1024, 64, 0, stream>>>(adj, ws);

  head_kernel<<<512, 256, 0, stream>>>(ws, d_out);
}